// Round 5
// baseline (412.958 us; speedup 1.0000x reference)
//
#include <hip/hip_runtime.h>
#include <math.h>

using u16 = unsigned short;
typedef __attribute__((ext_vector_type(8))) short short8;
typedef __attribute__((ext_vector_type(16))) float floatx16;

constexpr int Bc = 32, Nn = 500, Mm = 500, Dd = 256, MP = 512;
constexpr float LOGIT_CLIP = 10.0f;
constexpr float INV_SQRT_D = 1.0f / 16.0f;

__device__ __forceinline__ floatx16 mfma32(short8 a, short8 b, floatx16 c) {
    return __builtin_amdgcn_mfma_f32_32x32x16_bf16(a, b, c, 0, 0, 0);
}

__device__ __forceinline__ floatx16 zero16() {
    floatx16 v = {0.f,0.f,0.f,0.f,0.f,0.f,0.f,0.f,0.f,0.f,0.f,0.f,0.f,0.f,0.f,0.f};
    return v;
}

// async global->LDS DMA, 16 B per lane; LDS dest = wave-uniform base + lane*16
__device__ __forceinline__ void dma16(const void* g, void* l) {
    __builtin_amdgcn_global_load_lds(
        (const __attribute__((address_space(1))) void*)g,
        (__attribute__((address_space(3))) void*)l,
        16, 0, 0);
}

// split fp32 x into bf16 hi (RTN) + bf16 lo (RTN of residual): x ~= hi + lo
__device__ __forceinline__ void split1(float x, u16& h, u16& l) {
    unsigned u = __float_as_uint(x);
    unsigned rh = (u + 0x7FFFu + ((u >> 16) & 1u)) & 0xFFFF0000u;
    float fh = __uint_as_float(rh);
    float fl = x - fh;
    unsigned ul = __float_as_uint(fl);
    unsigned rl = ul + 0x7FFFu + ((ul >> 16) & 1u);
    h = (u16)(rh >> 16);
    l = (u16)(rl >> 16);
}

__device__ __forceinline__ u16 bf16rtn(float x) {
    unsigned u = __float_as_uint(x);
    return (u16)((u + 0x7FFFu + ((u >> 16) & 1u)) >> 16);
}

__device__ __forceinline__ float fast_tanh(float x) {
    return 1.0f - 2.0f / (__expf(2.0f * x) + 1.0f);
}

// ---------------------------------------------------------------------------
// K0w: weights fp32 -> bf16 hi/lo, 4 sources packed [Wk|Wv|Wq0|Wq1]
// ---------------------------------------------------------------------------
__global__ __launch_bounds__(256) void k0w(const float* __restrict__ s0,
                                           const float* __restrict__ s1,
                                           const float* __restrict__ s2,
                                           const float* __restrict__ s3,
                                           u16* __restrict__ hb, u16* __restrict__ lb,
                                           int nper) {
    const float* s = blockIdx.y == 0 ? s0 : blockIdx.y == 1 ? s1 :
                     blockIdx.y == 2 ? s2 : s3;
    u16* h = hb + (size_t)blockIdx.y * nper;
    u16* l = lb + (size_t)blockIdx.y * nper;
    const int i = (blockIdx.x * 256 + threadIdx.x) * 8;
    if (i >= nper) return;
    float4 a = *(const float4*)&s[i];
    float4 c = *(const float4*)&s[i + 4];
    short8 hv, lv; u16 hh, ll;
    split1(a.x, hh, ll); hv[0] = (short)hh; lv[0] = (short)ll;
    split1(a.y, hh, ll); hv[1] = (short)hh; lv[1] = (short)ll;
    split1(a.z, hh, ll); hv[2] = (short)hh; lv[2] = (short)ll;
    split1(a.w, hh, ll); hv[3] = (short)hh; lv[3] = (short)ll;
    split1(c.x, hh, ll); hv[4] = (short)hh; lv[4] = (short)ll;
    split1(c.y, hh, ll); hv[5] = (short)hh; lv[5] = (short)ll;
    split1(c.z, hh, ll); hv[6] = (short)hh; lv[6] = (short)ll;
    split1(c.w, hh, ll); hv[7] = (short)hh; lv[7] = (short)ll;
    *(short8*)&h[i] = hv;
    *(short8*)&l[i] = lv;
}

// K0s3: three sources (jobs,q0,q1) -> hi/lo regions, blockIdx.y picks
__global__ __launch_bounds__(256) void k0s3(const float* __restrict__ s0,
                                            const float* __restrict__ s1,
                                            const float* __restrict__ s2,
                                            u16* __restrict__ h0, u16* __restrict__ l0,
                                            u16* __restrict__ h1, u16* __restrict__ l1,
                                            u16* __restrict__ h2, u16* __restrict__ l2) {
    const float* s = blockIdx.y == 0 ? s0 : blockIdx.y == 1 ? s1 : s2;
    u16* h = blockIdx.y == 0 ? h0 : blockIdx.y == 1 ? h1 : h2;
    u16* l = blockIdx.y == 0 ? l0 : blockIdx.y == 1 ? l1 : l2;
    const int i = (blockIdx.x * 256 + threadIdx.x) * 8;
    float4 a = *(const float4*)&s[i];
    float4 c = *(const float4*)&s[i + 4];
    short8 hv, lv; u16 hh, ll;
    split1(a.x, hh, ll); hv[0] = (short)hh; lv[0] = (short)ll;
    split1(a.y, hh, ll); hv[1] = (short)hh; lv[1] = (short)ll;
    split1(a.z, hh, ll); hv[2] = (short)hh; lv[2] = (short)ll;
    split1(a.w, hh, ll); hv[3] = (short)hh; lv[3] = (short)ll;
    split1(c.x, hh, ll); hv[4] = (short)hh; lv[4] = (short)ll;
    split1(c.y, hh, ll); hv[5] = (short)hh; lv[5] = (short)ll;
    split1(c.z, hh, ll); hv[6] = (short)hh; lv[6] = (short)ll;
    split1(c.w, hh, ll); hv[7] = (short)hh; lv[7] = (short)ll;
    *(short8*)&h[i] = hv;
    *(short8*)&l[i] = lv;
}

// ---------------------------------------------------------------------------
// KEXP: expb[b][n][mp] = bf16( exp(-a1*ls*cost + mask) ), m-padded to 512 w/ 0
// ---------------------------------------------------------------------------
__global__ __launch_bounds__(256) void kexp(const float* __restrict__ cost,
                                            const float* __restrict__ mask,
                                            const float* __restrict__ alpha1,
                                            const float* __restrict__ lsc,
                                            u16* __restrict__ expbH) {
    const float a1ls = alpha1[0] * lsc[0];
    const int row = blockIdx.x * 2 + (threadIdx.x >> 7);  // 0..15999
    const int m0 = (threadIdx.x & 127) * 4;
    ushort4 w;
    if (m0 < Mm) {
        const size_t o = (size_t)row * Mm + m0;
        float4 cc = *(const float4*)&cost[o];
        float4 mm = *(const float4*)&mask[o];
        w.x = bf16rtn(__expf(fmaf(-a1ls, cc.x, mm.x)));
        w.y = bf16rtn(__expf(fmaf(-a1ls, cc.y, mm.y)));
        w.z = bf16rtn(__expf(fmaf(-a1ls, cc.z, mm.z)));
        w.w = bf16rtn(__expf(fmaf(-a1ls, cc.w, mm.w)));
    } else {
        w.x = 0; w.y = 0; w.z = 0; w.w = 0;
    }
    *(ushort4*)&expbH[(size_t)row * MP + m0] = w;
}

// ---------------------------------------------------------------------------
// K1: ekT[b][d][m]=exp(k), ekvT=ek*v; k/v = jobs@Wk^T/Wv^T; split-bf16 hi/lo out
// ---------------------------------------------------------------------------
__global__ __launch_bounds__(256) void k1_kv(const u16* __restrict__ jobsH,
                                             const u16* __restrict__ jobsL,
                                             const u16* __restrict__ wH,
                                             const u16* __restrict__ wL,
                                             u16* __restrict__ ekTH, u16* __restrict__ ekTL,
                                             u16* __restrict__ ekvTH, u16* __restrict__ ekvTL) {
    const int lane = threadIdx.x & 63, wv = threadIdx.x >> 6;
    const int l31 = lane & 31, h = lane >> 5;
    const int b = blockIdx.z;
    const int D0 = blockIdx.y * 128 + wv * 32;
    const int M0 = blockIdx.x * 64;

    const size_t ar = (size_t)(D0 + l31) * Dd + h * 8;
    const size_t jr0 = ((size_t)b * Mm + min(M0 + l31, Mm - 1)) * Dd + h * 8;
    const size_t jr1 = ((size_t)b * Mm + min(M0 + 32 + l31, Mm - 1)) * Dd + h * 8;

    floatx16 ak0 = zero16(), ak1 = zero16(), av0 = zero16(), av1 = zero16();

#pragma unroll
    for (int t = 0; t < Dd; t += 16) {
        short8 kh = *(const short8*)(wH + ar + t);
        short8 kl = *(const short8*)(wL + ar + t);
        short8 vh = *(const short8*)(wH + 65536 + ar + t);
        short8 vl = *(const short8*)(wL + 65536 + ar + t);
        short8 b0h = *(const short8*)(jobsH + jr0 + t);
        short8 b0l = *(const short8*)(jobsL + jr0 + t);
        short8 b1h = *(const short8*)(jobsH + jr1 + t);
        short8 b1l = *(const short8*)(jobsL + jr1 + t);
        ak0 = mfma32(kh, b0h, ak0); ak0 = mfma32(kh, b0l, ak0); ak0 = mfma32(kl, b0h, ak0);
        av0 = mfma32(vh, b0h, av0); av0 = mfma32(vh, b0l, av0); av0 = mfma32(vl, b0h, av0);
        ak1 = mfma32(kh, b1h, ak1); ak1 = mfma32(kh, b1l, ak1); ak1 = mfma32(kl, b1h, ak1);
        av1 = mfma32(vh, b1h, av1); av1 = mfma32(vh, b1l, av1); av1 = mfma32(vl, b1h, av1);
    }

#pragma unroll
    for (int r = 0; r < 16; ++r) {
        const int d = D0 + (r & 3) + ((r >> 2) << 3) + (h << 2);
        const size_t dbase = ((size_t)b * Dd + d) * MP;
        const int m0 = M0 + l31;
        if (m0 < Mm) {
            const float ek = __expf(ak0[r]);
            const float ev = ek * av0[r];
            u16 hh, ll;
            split1(ek, hh, ll); ekTH[dbase + m0] = hh; ekTL[dbase + m0] = ll;
            split1(ev, hh, ll); ekvTH[dbase + m0] = hh; ekvTL[dbase + m0] = ll;
        }
        const int m1 = m0 + 32;
        if (m1 < Mm) {
            const float ek = __expf(ak1[r]);
            const float ev = ek * av1[r];
            u16 hh, ll;
            split1(ek, hh, ll); ekTH[dbase + m1] = hh; ekTL[dbase + m1] = ll;
            split1(ev, hh, ll); ekvTH[dbase + m1] = hh; ekvTL[dbase + m1] = ll;
        }
    }
}

// ---------------------------------------------------------------------------
// K2: sq[b][n][d] = sigmoid(q0@Wq0^T + q1@Wq1^T), fp32 out.
// ---------------------------------------------------------------------------
__global__ __launch_bounds__(256) void k2_q(const u16* __restrict__ q0H, const u16* __restrict__ q0L,
                                            const u16* __restrict__ q1H, const u16* __restrict__ q1L,
                                            const u16* __restrict__ wH, const u16* __restrict__ wL,
                                            float* __restrict__ sq) {
    const int lane = threadIdx.x & 63, wv = threadIdx.x >> 6;
    const int l31 = lane & 31, h = lane >> 5;
    const int b = blockIdx.z;
    const int N0 = blockIdx.y * 128 + wv * 32;
    const int D0 = blockIdx.x * 64;

    const size_t ar  = ((size_t)b * Nn + min(N0 + l31, Nn - 1)) * Dd + h * 8;
    const size_t wr0 = (size_t)(D0 + l31) * Dd + h * 8;
    const size_t wr1 = (size_t)(D0 + 32 + l31) * Dd + h * 8;
    const u16* W0H = wH + 131072; const u16* W0L = wL + 131072;
    const u16* W1H = wH + 196608; const u16* W1L = wL + 196608;

    floatx16 acc0 = zero16(), acc1 = zero16();

#pragma unroll
    for (int t = 0; t < Dd; t += 16) {
        short8 a0h = *(const short8*)(q0H + ar + t);
        short8 a0l = *(const short8*)(q0L + ar + t);
        short8 a1h = *(const short8*)(q1H + ar + t);
        short8 a1l = *(const short8*)(q1L + ar + t);
        short8 b00h = *(const short8*)(W0H + wr0 + t);
        short8 b00l = *(const short8*)(W0L + wr0 + t);
        short8 b10h = *(const short8*)(W1H + wr0 + t);
        short8 b10l = *(const short8*)(W1L + wr0 + t);
        short8 b01h = *(const short8*)(W0H + wr1 + t);
        short8 b01l = *(const short8*)(W0L + wr1 + t);
        short8 b11h = *(const short8*)(W1H + wr1 + t);
        short8 b11l = *(const short8*)(W1L + wr1 + t);
        acc0 = mfma32(a0h, b00h, acc0); acc0 = mfma32(a0h, b00l, acc0); acc0 = mfma32(a0l, b00h, acc0);
        acc0 = mfma32(a1h, b10h, acc0); acc0 = mfma32(a1h, b10l, acc0); acc0 = mfma32(a1l, b10h, acc0);
        acc1 = mfma32(a0h, b01h, acc1); acc1 = mfma32(a0h, b01l, acc1); acc1 = mfma32(a0l, b01h, acc1);
        acc1 = mfma32(a1h, b11h, acc1); acc1 = mfma32(a1h, b11l, acc1); acc1 = mfma32(a1l, b11h, acc1);
    }

#pragma unroll
    for (int r = 0; r < 16; ++r) {
        const int n = N0 + (r & 3) + ((r >> 2) << 3) + (h << 2);
        if (n < Nn) {
            const size_t o = ((size_t)b * Nn + n) * Dd + D0 + l31;
            sq[o]      = 1.0f / (1.0f + __expf(-acc0[r]));
            sq[o + 32] = 1.0f / (1.0f + __expf(-acc1[r]));
        }
    }
}

// ---------------------------------------------------------------------------
// K3: num/den = expb @ (ekvT/ekT)^T over m (K=512 padded); aafm = sq*num/den.
// m97-style: B operands DMA'd to double-buffered LDS via global_load_lds;
// A (expb) direct-loaded. Block 4 waves = 32n x 256d; 32 chunks of 16 m.
// Grid flat 512, b-colocating XCD swizzle.
// ---------------------------------------------------------------------------
__global__ __launch_bounds__(256) void k3_aafm(const u16* __restrict__ expbH,
                                               const u16* __restrict__ ekTH, const u16* __restrict__ ekTL,
                                               const u16* __restrict__ ekvTH, const u16* __restrict__ ekvTL,
                                               const float* __restrict__ sq,
                                               u16* __restrict__ aafmH, u16* __restrict__ aafmL) {
    __shared__ __align__(16) u16 Bs[2][32][512];  // 2 x 32 cells x 1 KB = 64 KB
    const int i = blockIdx.x;
    const int x = i & 7, j = i >> 3;
    const int nt = j & 15;
    const int b = ((j >> 4) << 3) + x;      // 16 nt of each b co-located on one XCD
    const int lane = threadIdx.x & 63, wv = threadIdx.x >> 6;
    const int l31 = lane & 31, h = lane >> 5;
    const int N0 = nt << 5;
    const size_t eb = (size_t)b * Dd;

    // wave wv stages+computes d-tiles {2wv, 2wv+1}; cell jj: dt=2wv+(jj>>2), buf=jj&3
    const u16* bp[4] = {ekTH, ekTL, ekvTH, ekvTL};
    const u16* src[8];
#pragma unroll
    for (int jj = 0; jj < 8; ++jj) {
        const int dt = 2 * wv + (jj >> 2), bf = jj & 3;
        src[jj] = bp[bf] + (eb + dt * 32 + l31) * MP + h * 8;
    }
    const size_t arow = ((size_t)b * Nn + min(N0 + l31, Nn - 1)) * MP + h * 8;

    floatx16 dn0 = zero16(), dn1 = zero16(), nm0 = zero16(), nm1 = zero16();

#define K3DMA(MC, BUF) { \
    _Pragma("unroll") \
    for (int jj = 0; jj < 8; ++jj) \
        dma16(src[jj] + (MC), &Bs[BUF][wv * 8 + jj][0]); }

    K3DMA(0, 0)
#pragma unroll 1
    for (int c = 0; c < 32; ++c) {
        __syncthreads();                       // drains DMA of chunk c; fences buf reuse
        if (c + 1 < 32) { K3DMA((c + 1) * 16, (c + 1) & 1) }
        const int cb = c & 1;
        const short8 A   = *(const short8*)(expbH + arow + c * 16);
        const short8 e0h = *(const short8*)&Bs[cb][wv * 8 + 0][lane * 8];
        const short8 e0l = *(const short8*)&Bs[cb][wv * 8 + 1][lane * 8];
        const short8 v0h = *(const short8*)&Bs[cb][wv * 8 + 2][lane * 8];
        const short8 v0l = *(const short8*)&Bs[cb][wv * 8 + 3][lane * 8];
        const short8 e1h = *(const short8*)&Bs[cb][wv * 8 + 4][lane * 8];
        const short8 e1l = *(const short8*)&Bs[cb][wv * 8 + 5][lane * 8];
        const short8 v1h = *(const short8*)&Bs[cb][wv * 8 + 6][lane * 8];
        const short8 v1l = *(const short8*)&Bs[cb][wv * 8 + 7][lane * 8];
        dn0 = mfma32(A, e0h, dn0); dn0 = mfma32(A, e0l, dn0);
        nm0 = mfma32(A, v0h, nm0); nm0 = mfma32(A, v0l, nm0);
        dn1 = mfma32(A, e1h, dn1); dn1 = mfma32(A, e1l, dn1);
        nm1 = mfma32(A, v1h, nm1); nm1 = mfma32(A, v1l, nm1);
    }
#undef K3DMA

#pragma unroll
    for (int r = 0; r < 16; ++r) {
        const int n = N0 + (r & 3) + ((r >> 2) << 3) + (h << 2);
        if (n < Nn) {
            const size_t o0 = ((size_t)b * Nn + n) * Dd + (wv << 6) + l31;
            u16 hh, ll;
            const float d0 = dn0[r];
            const float w0 = (d0 != 0.f) ? nm0[r] / d0 : 0.f;
            split1(sq[o0] * w0, hh, ll); aafmH[o0] = hh; aafmL[o0] = ll;
            const size_t o1 = o0 + 32;
            const float d1 = dn1[r];
            const float w1 = (d1 != 0.f) ? nm1[r] / d1 : 0.f;
            split1(sq[o1] * w1, hh, ll); aafmH[o1] = hh; aafmL[o1] = ll;
        }
    }
}

// ---------------------------------------------------------------------------
// K4: logits = 10*tanh((aafm@jobs^T)/16 - a2*ls*cost) + mask, FUSED row softmax.
// jobs H/L DMA'd to double-buffered LDS; aafm direct. Block 8 waves = 32n x 512m.
// pred[] aliases the staging LDS after the K-loop. Grid flat 512, b-swizzled.
// ---------------------------------------------------------------------------
__global__ __launch_bounds__(512, 4) void k4_score(const u16* __restrict__ aafmH,
                                                   const u16* __restrict__ aafmL,
                                                   const u16* __restrict__ jobsH,
                                                   const u16* __restrict__ jobsL,
                                                   const float* __restrict__ cost,
                                                   const float* __restrict__ mask,
                                                   const float* __restrict__ alpha2,
                                                   const float* __restrict__ lsc,
                                                   float* __restrict__ out) {
    __shared__ __align__(16) u16 Bs[2][32][512];  // 64 KB; reused as pred after K-loop
    float* predf = (float*)&Bs[0][0][0];          // [row 0..31][wv 0..7]
    const int i = blockIdx.x;
    const int x = i & 7, j = i >> 3;
    const int nt = j & 15;
    const int b = ((j >> 4) << 3) + x;
    const int lane = threadIdx.x & 63, wv = threadIdx.x >> 6;  // wv 0..7
    const int l31 = lane & 31, h = lane >> 5;
    const int N0 = nt << 5;
    const float a2ls = alpha2[0] * lsc[0];

    // wave wv owns m in [wv*64, wv*64+64); cell jj: mt=jj>>1, buf=jj&1 (H/L)
    const u16* jp[2] = {jobsH, jobsL};
    const u16* src[4];
#pragma unroll
    for (int jj = 0; jj < 4; ++jj) {
        const int mt = jj >> 1, bf = jj & 1;
        const int m = wv * 64 + mt * 32 + l31;
        src[jj] = jp[bf] + ((size_t)b * Mm + min(m, Mm - 1)) * Dd + h * 8;
    }
    const size_t arow = ((size_t)b * Nn + min(N0 + l31, Nn - 1)) * Dd + h * 8;
    const int m0g = wv * 64 + l31;
    const int m1g = m0g + 32;

    floatx16 acc0 = zero16(), acc1 = zero16();

#define K4DMA(TC, BUF) { \
    _Pragma("unroll") \
    for (int jj = 0; jj < 4; ++jj) \
        dma16(src[jj] + (TC), &Bs[BUF][wv * 4 + jj][0]); }

    K4DMA(0, 0)
#pragma unroll 1
    for (int c = 0; c < 16; ++c) {
        __syncthreads();
        if (c + 1 < 16) { K4DMA((c + 1) * 16, (c + 1) & 1) }
        const int cb = c & 1;
        const short8 aH  = *(const short8*)(aafmH + arow + c * 16);
        const short8 aL  = *(const short8*)(aafmL + arow + c * 16);
        const short8 j0h = *(const short8*)&Bs[cb][wv * 4 + 0][lane * 8];
        const short8 j0l = *(const short8*)&Bs[cb][wv * 4 + 1][lane * 8];
        const short8 j1h = *(const short8*)&Bs[cb][wv * 4 + 2][lane * 8];
        const short8 j1l = *(const short8*)&Bs[cb][wv * 4 + 3][lane * 8];
        acc0 = mfma32(aH, j0h, acc0); acc0 = mfma32(aH, j0l, acc0); acc0 = mfma32(aL, j0h, acc0);
        acc1 = mfma32(aH, j1h, acc1); acc1 = mfma32(aH, j1l, acc1); acc1 = mfma32(aL, j1h, acc1);
    }
#undef K4DMA
    __syncthreads();   // all waves done with Bs -> safe to alias predf

    // ---- epilogue: logits ----
    float lg0[16], lg1[16];
    const size_t cb2 = (size_t)b * Nn * Mm;
#pragma unroll
    for (int r = 0; r < 16; ++r) {
        const int row = (r & 3) + ((r >> 2) << 3) + (h << 2);
        const int n = N0 + row;
        if (n < Nn) {
            const size_t o = cb2 + (size_t)n * Mm + m0g;
            lg0[r] = LOGIT_CLIP * fast_tanh(fmaf(-a2ls, cost[o], acc0[r] * INV_SQRT_D)) + mask[o];
            if (m1g < Mm) {
                const size_t o1 = o + 32;
                lg1[r] = LOGIT_CLIP * fast_tanh(fmaf(-a2ls, cost[o1], acc1[r] * INV_SQRT_D)) + mask[o1];
            } else lg1[r] = -1e30f;
        } else { lg0[r] = -1e30f; lg1[r] = -1e30f; }
    }

    // ---- row max: butterfly within 32-lane half, then cross-wave via LDS ----
    float rm[16];
#pragma unroll
    for (int r = 0; r < 16; ++r) rm[r] = fmaxf(lg0[r], lg1[r]);
#pragma unroll
    for (int d = 1; d < 32; d <<= 1)
#pragma unroll
        for (int r = 0; r < 16; ++r) rm[r] = fmaxf(rm[r], __shfl_xor(rm[r], d));
    if (l31 == 0) {
#pragma unroll
        for (int r = 0; r < 16; ++r)
            predf[((r & 3) + ((r >> 2) << 3) + (h << 2)) * 8 + wv] = rm[r];
    }
    __syncthreads();
    float fm[16];
#pragma unroll
    for (int r = 0; r < 16; ++r) {
        const int row = (r & 3) + ((r >> 2) << 3) + (h << 2);
        float v = predf[row * 8 + 0];
#pragma unroll
        for (int w = 1; w < 8; ++w) v = fmaxf(v, predf[row * 8 + w]);
        fm[r] = v;
    }
    __syncthreads();

    // ---- exp + row sum ----
    float sm[16];
#pragma unroll
    for (int r = 0; r < 16; ++r) {
        lg0[r] = __expf(lg0[r] - fm[r]);
        lg1[r] = __expf(lg1[r] - fm[r]);
        sm[r] = lg0[r] + lg1[r];
    }
#pragma unroll
    for (int d = 1; d < 32; d <<= 1)
#pragma unroll
        for (int r = 0; r < 16; ++r) sm[r] += __shfl_xor(sm[r], d);
    if (l31 == 0) {
#pragma unroll
        for (int r = 0; r < 16; ++r)
            predf[((r & 3) + ((r >> 2) << 3) + (h << 2)) * 8 + wv] = sm[r];
    }
    __syncthreads();

    // ---- normalize + store ----
#pragma unroll
    for (int r = 0; r < 16; ++r) {
        const int row = (r & 3) + ((r >> 2) << 3) + (h << 2);
        const int n = N0 + row;
        if (n < Nn) {
            float s = predf[row * 8 + 0];
#pragma unroll
            for (int w = 1; w < 8; ++w) s += predf[row * 8 + w];
            const float inv = 1.0f / s;
            const size_t o = cb2 + (size_t)n * Mm + m0g;
            out[o] = lg0[r] * inv;
            if (m1g < Mm) out[o + 32] = lg1[r] * inv;
        }
    }
}

// ---------------------------------------------------------------------------
extern "C" void kernel_launch(void* const* d_in, const int* in_sizes, int n_in,
                              void* d_out, int out_size, void* d_ws, size_t ws_size,
                              hipStream_t stream) {
    const float* q0        = (const float*)d_in[0];
    const float* jobs      = (const float*)d_in[1];
    const float* q1        = (const float*)d_in[2];
    const float* cost      = (const float*)d_in[3];
    const float* log_scale = (const float*)d_in[4];
    const float* mask      = (const float*)d_in[5];
    const float* Wq0       = (const float*)d_in[6];
    const float* Wq1       = (const float*)d_in[7];
    const float* Wk        = (const float*)d_in[8];
    const float* Wv        = (const float*)d_in[9];
    const float* alpha1    = (const float*)d_in[10];
    const float* alpha2    = (const float*)d_in[11];
    float* out = (float*)d_out;

    const size_t NBD = (size_t)Bc * Nn * Dd;   // 4,096,000
    const size_t BTP = (size_t)Bc * Dd * MP;   // 4,194,304

    u16* ws    = (u16*)d_ws;
    u16* jobsH = ws;                 // [jobsH | q0H | q1H | q1L | q0L | jobsL]
    u16* q0H   = ws + NBD;
    u16* q1H   = ws + 2 * NBD;       // } expbH aliases q1H..q1L (2*NBD exact)
    u16* q1L   = ws + 3 * NBD;
    u16* q0L   = ws + 4 * NBD;
    u16* jobsL = ws + 5 * NBD;
    u16* wH    = ws + 6 * NBD;       // [Wk|Wv|Wq0|Wq1] hi
    u16* wL    = wH + 4 * 65536;
    u16* ekTH  = wL + 4 * 65536;
    u16* ekTL  = ekTH + BTP;
    u16* ekvTH = ekTL + BTP;
    u16* ekvTL = ekvTH + BTP;
    float* sq  = (float*)(ekvTL + BTP);  // 4,096,000 fp32

    u16* expbH = q1H;   // valid after k2 (q1 splits dead)
    u16* aafmH = q0H;   // valid after k2 (q0 splits dead)
    u16* aafmL = q0L;

    dim3 blk(256);
    k0w<<<dim3(32, 4), blk, 0, stream>>>(Wk, Wv, Wq0, Wq1, wH, wL, Dd * Dd);
    k0s3<<<dim3(2000, 3), blk, 0, stream>>>(jobs, q0, q1, jobsH, jobsL, q0H, q0L, q1H, q1L);
    k1_kv<<<dim3(8, 2, 32), blk, 0, stream>>>(jobsH, jobsL, wH, wL, ekTH, ekTL, ekvTH, ekvTL);
    k2_q<<<dim3(4, 4, 32), blk, 0, stream>>>(q0H, q0L, q1H, q1L, wH, wL, sq);
    kexp<<<8000, blk, 0, stream>>>(cost, mask, alpha1, log_scale, expbH);
    k3_aafm<<<512, blk, 0, stream>>>(expbH, ekTH, ekTL, ekvTH, ekvTL, sq, aafmH, aafmL);
    k4_score<<<512, dim3(512), 0, stream>>>(aafmH, aafmL, jobsH, jobsL, cost, mask,
                                            alpha2, log_scale, out);
}